// Round 12
// baseline (127.727 us; speedup 1.0000x reference)
//
#include <hip/hip_runtime.h>
#include <hip/hip_bf16.h>
#include <cstddef>

#define EPSV 1e-5f

typedef __attribute__((ext_vector_type(8))) short bf16x8;
typedef __attribute__((ext_vector_type(4))) float f32x4;
typedef __attribute__((ext_vector_type(4))) short short4v;
typedef __attribute__((ext_vector_type(4))) int int4v;

__device__ __forceinline__ float b2f(short s) {
  union { unsigned u; float f; } x;
  x.u = ((unsigned)(unsigned short)s) << 16;
  return x.f;
}
__device__ __forceinline__ short f2b(float f) {
  union { __hip_bfloat16 h; short s; } x;
  x.h = __float2bfloat16(f);
  return x.s;
}

// ---- prep region layout (float offsets inside d_out) ----
// d_out floats: [0, 3211264) = xbT bf16 [896][56][128]  (as shorts)
#define PF_W    3300000   // bf16 [8][32][128]   = 16384 f
#define PF_RQP  3316384   // bf16 [8][112][40]   = 17920 f (K-packed: relq dup cols 0..15, rest 0)
#define PF_RKP  3334304   // bf16 [8][112][40]   = 17920 f (relk dup cols 16..31, rest 0)
#define PF_RV   3352224   // bf16 [8][16][136]   = 8704 f  (zero-padded d>=111)
#define PF_QSC  3360928   // f32 [256]  (k-rows scA-folded)
#define PF_QSH  3361184   // f32 [256]
#define PF_OSC  3361440   // f32 [256]
#define PF_OSH  3361696   // f32 [256]
#define PF_SH3  3361952   // f32 [8]

// Block-invariant precompute: W->bf16, rel->packed MFMA tables, BN folds.
__global__ __launch_bounds__(256) void k_prep(
    const float* __restrict__ wq, const float* __restrict__ rel,
    const float* __restrict__ qg, const float* __restrict__ qb,
    const float* __restrict__ qm, const float* __restrict__ qv,
    const float* __restrict__ sg, const float* __restrict__ sb,
    const float* __restrict__ sm, const float* __restrict__ svar,
    const float* __restrict__ og, const float* __restrict__ ob,
    const float* __restrict__ om, const float* __restrict__ ov,
    float* __restrict__ prep) {
  const int g = blockIdx.x;
  const int tid = threadIdx.x;
  const float scA = sg[g] * rsqrtf(svar[g] + EPSV);
  const float scB = sg[8 + g] * rsqrtf(svar[8 + g] + EPSV);
  const float scC = sg[16 + g] * rsqrtf(svar[16 + g] + EPSV);
  const float rCA = scC / scA;

  short* wb = (short*)(prep + PF_W) + g * 4096;
  for (int t = tid; t < 1024; t += 256) {
    int o = t >> 5, c0 = (t & 31) * 4;
    float4 wv = *(const float4*)&wq[g * 4096 + o * 128 + c0];
    short4v s4 = {f2b(wv.x), f2b(wv.y), f2b(wv.z), f2b(wv.w)};
    *(short4v*)&wb[o * 128 + c0] = s4;
  }
  // K-packed rel tables for T/U MFMA (A = [qh|ql|kh|kl] cols 0..31):
  // rqp row d: cols 0..15 = scB*relq[c&7][d] (dup), cols 16..39 = 0
  // rkp row d: cols 16..31 = rCA*relk[c&7][d] (dup), cols 0..15 & 32..39 = 0
  short* rqp = (short*)(prep + PF_RQP) + g * 4480;
  short* rkp = (short*)(prep + PF_RKP) + g * 4480;
  for (int t = tid; t < 4480; t += 256) {
    int d = t / 40, c = t - d * 40;
    short vq = 0, vk = 0;
    if (d < 111) {
      if (c < 16) vq = f2b(rel[(c & 7) * 111 + d] * scB);
      else if (c < 32) vk = f2b(rel[(8 + (c & 7)) * 111 + d] * rCA);
    }
    rqp[t] = vq;
    rkp[t] = vk;
  }
  short* rv = (short*)(prep + PF_RV) + g * 2176;
  for (int t = tid; t < 2176; t += 256) {
    int c = t / 136, d = t - c * 136;
    rv[t] = (d < 111) ? f2b(rel[(16 + c) * 111 + d]) : (short)0;
  }
  if (tid < 32) {
    int ch = g * 32 + tid;
    float sc = qg[ch] * rsqrtf(qv[ch] + EPSV);
    float sh = qb[ch] - qm[ch] * sc;
    if (tid >= 8 && tid < 16) { sc *= scA; sh *= scA; }   // k' = scA * k_bn
    prep[PF_QSC + ch] = sc;
    prep[PF_QSH + ch] = sh;
    float so = og[ch] * rsqrtf(ov[ch] + EPSV);
    prep[PF_OSC + ch] = so;
    prep[PF_OSH + ch] = ob[ch] - om[ch] * so;
  }
  if (tid == 0) {
    float shA = sb[g] - sm[g] * scA;
    float shB = sb[8 + g] - sm[8 + g] * scB;
    float shC = sb[16 + g] - sm[16 + g] * scC;
    prep[PF_SH3 + g] = shA + shB + shC;
  }
}

// x (16,128,56,56) f32 -> xbT bf16 [896][56][128]: xbT[n*56+w][h][c] = bf16(x[n][c][h][w])
__global__ __launch_bounds__(256) void k_transpose_in(const float* __restrict__ x,
                                                      unsigned* __restrict__ xbT) {
  const int nh = blockIdx.x;              // n*56 + h
  const int n = nh / 56, h = nh - n * 56;
  __shared__ short t2[128 * 57];
  const float* src = x + (size_t)n * 401408 + h * 56;
  for (int t = threadIdx.x; t < 1792; t += 256) {
    int c = t / 14, w4 = (t - c * 14) * 4;
    float4 v = *(const float4*)&src[c * 3136 + w4];
    t2[c * 57 + w4 + 0] = f2b(v.x);
    t2[c * 57 + w4 + 1] = f2b(v.y);
    t2[c * 57 + w4 + 2] = f2b(v.z);
    t2[c * 57 + w4 + 3] = f2b(v.w);
  }
  __syncthreads();
  for (int t = threadIdx.x; t < 3584; t += 256) {
    int w = t >> 6, cp = t & 63;
    unsigned lo = (unsigned short)t2[(2 * cp) * 57 + w];
    unsigned hi = (unsigned short)t2[(2 * cp + 1) * 57 + w];
    xbT[(((size_t)(n * 56 + w) * 56 + h) << 6) + cp] = lo | (hi << 16);
  }
}

// tmp (896,128,56) -> out (16,128,56,56)
__global__ __launch_bounds__(256) void k_transpose_out(const float* __restrict__ tmp,
                                                       float* __restrict__ out) {
  int nc = blockIdx.x;
  int n = nc >> 7, c = nc & 127;
  __shared__ float t[56][57];
  for (int idx = threadIdx.x; idx < 3136; idx += 256) {
    int w = idx / 56, h = idx - w * 56;
    t[h][w] = tmp[((size_t)(n * 56 + w) * 128 + c) * 56 + h];
  }
  __syncthreads();
  float* dst = out + (size_t)nc * 3136;
  for (int idx = threadIdx.x; idx < 3136; idx += 256)
    dst[idx] = t[idx / 56][idx % 56];
}

// LDS arena (offsets in shorts). Lifetime unions:
//  R1 [0,12656): xsT[56][136]+Ws[32][136] (A..B) | T f32 [56][113] (T..G) |
//                UT f32 [111][57] (U..C) | simShift[64][120]+simA[64][72] (S..D)
//  [12656,14896): qkT f32 [56][20] (B..C) | svL f32 [16][60] (D..E)
//  [14896,17456): qkA bf16 [64][40] = [qh|ql|kh|kl] (B..U; rows 56..63 stale->discarded D-rows)
//  [17456,21936): rB bf16 [112][40] (A: rqB; G restage: rkB) | relv bf16 [16][136] (S..D)
//  [21936,23088): VBH bf16 [16][72];  [23088,24240): VBL bf16 [16][72]
#define O_XST    0
#define O_WS     7616
#define O_SHFT   0
#define O_SIMA   7680
#define O_QKT    12656
#define O_SVL    12656
#define O_QKA    14896
#define O_RB     17456
#define O_RELV   17456
#define O_VBH    21936
#define O_VBL    23088
#define SB_SH    24240

// One block per (b,g): bid = g*896 + b. LDS ~48.5 KB -> 3 blocks/CU.
__global__ __launch_bounds__(512) void k_fused(
    const short* __restrict__ xbT, const float* __restrict__ prep,
    float* __restrict__ tmp) {
  const int tid = threadIdx.x;
  const int g = blockIdx.x / 896;
  const int b = blockIdx.x - g * 896;

  __shared__ __align__(16) short SB[SB_SH];
  __shared__ float s_qsc[32], s_qsh[32], s_osc[32], s_osh[32], s_sh3;

  const int lane = tid & 63;
  const int w = tid >> 6;          // wave 0..7
  const int m = lane & 15;
  const int qd = lane >> 4;        // 0..3
  const int it = w >> 1;           // tile row group 0..3
  const int half = w & 1;
  const int grp = tid >> 4;        // 16-lane group 0..31
  const int l16 = tid & 15;

  // ---------- phase A: pure-copy staging ----------
  {
    int4v z = {0, 0, 0, 0};
    int4v* zp = (int4v*)(SB + O_VBH);                 // VBH+VBL = 2304 sh = 288 int4
    for (int i = tid; i < 288; i += 512) zp[i] = z;

    const short* xsrc = xbT + (size_t)b * 7168;       // [56][128] bf16
    for (int t = tid; t < 896; t += 512) {
      int h = t >> 4, ck = (t & 15) * 8;
      *(bf16x8*)&SB[O_XST + h * 136 + ck] = *(const bf16x8*)&xsrc[h * 128 + ck];
    }
    const short* wsrc = (const short*)(prep + PF_W) + g * 4096;
    for (int t = tid; t < 512; t += 512) {
      int o = t >> 4, ck = (t & 15) * 8;
      *(bf16x8*)&SB[O_WS + o * 136 + ck] = *(const bf16x8*)&wsrc[o * 128 + ck];
    }
    const int4v* rqsrc = (const int4v*)((const short*)(prep + PF_RQP) + g * 4480);
    int4v* rbd = (int4v*)(SB + O_RB);
    for (int t = tid; t < 560; t += 512) rbd[t] = rqsrc[t];
    if (tid < 32) {
      s_qsc[tid] = prep[PF_QSC + g * 32 + tid];
      s_qsh[tid] = prep[PF_QSH + g * 32 + tid];
      s_osc[tid] = prep[PF_OSC + g * 32 + tid];
      s_osh[tid] = prep[PF_OSH + g * 32 + tid];
    }
    if (tid == 0) s_sh3 = prep[PF_SH3 + g];
  }
  __syncthreads();   // B0

  // ---------- phase B: qkv = BN(W @ x) MFMA; q,k' -> qkT f32 + qkA hi/lo; v -> VB ----------
  {
    const int o = half * 16 + m;
    const int h = it * 16 + m;
    f32x4 acc = {0.f, 0.f, 0.f, 0.f};
#pragma unroll
    for (int ks = 0; ks < 4; ++ks) {
      bf16x8 av = *(bf16x8*)&SB[O_WS + o * 136 + qd * 8 + ks * 32];
      bf16x8 bv = *(bf16x8*)&SB[O_XST + h * 136 + qd * 8 + ks * 32];
      acc = __builtin_amdgcn_mfma_f32_16x16x32_bf16(av, bv, acc, 0, 0, 0);
    }
    if (h < 56) {
      float* qkTf = (float*)(SB + O_QKT);
      if (half == 0) {               // q rows 0..7, k' rows 8..15
        float v4[4];
#pragma unroll
        for (int r = 0; r < 4; ++r)
          v4[r] = fmaf(acc[r], s_qsc[qd * 4 + r], s_qsh[qd * 4 + r]);
        float4 o4 = {v4[0], v4[1], v4[2], v4[3]};
        *(float4*)&qkTf[h * 20 + qd * 4] = o4;
#pragma unroll
        for (int r = 0; r < 4; ++r) {
          int oo = qd * 4 + r;
          short vh = f2b(v4[r]);
          short vl = f2b(v4[r] - b2f(vh));
          if (oo < 8) {              // qh col oo, ql col 8+oo
            SB[O_QKA + h * 40 + oo] = vh;
            SB[O_QKA + h * 40 + 8 + oo] = vl;
          } else {                   // kh col 8+oo (16..23), kl col 16+oo (24..31)
            SB[O_QKA + h * 40 + 8 + oo] = vh;
            SB[O_QKA + h * 40 + 16 + oo] = vl;
          }
        }
      } else {                       // v rows
#pragma unroll
        for (int r = 0; r < 4; ++r) {
          int cv = qd * 4 + r;
          float val = fmaf(acc[r], s_qsc[16 + cv], s_qsh[16 + cv]);
          short vh = f2b(val);
          short vl = f2b(val - b2f(vh));
          SB[O_VBH + cv * 72 + h] = vh;
          SB[O_VBL + cv * 72 + h] = vl;
        }
      }
    }
  }
  __syncthreads();   // B1

  // ---------- phase T: T = (qh+ql)@relq' MFMA -> T f32 [56][113] (over xsT/Ws) ----------
  float* Tf = (float*)SB;
  for (int tau = w; tau < 28; tau += 8) {
    int itT = tau / 7, ct = tau - itT * 7;
    bf16x8 av = *(bf16x8*)&SB[O_QKA + (itT * 16 + m) * 40 + qd * 8];
    bf16x8 bv = *(bf16x8*)&SB[O_RB + (ct * 16 + m) * 40 + qd * 8];
    f32x4 t0 = {0.f, 0.f, 0.f, 0.f};
    t0 = __builtin_amdgcn_mfma_f32_16x16x32_bf16(av, bv, t0, 0, 0, 0);
#pragma unroll
    for (int r = 0; r < 4; ++r) {
      int i2 = itT * 16 + qd * 4 + r;
      if (i2 < 56) Tf[i2 * 113 + ct * 16 + m] = t0[r];
    }
  }
  __syncthreads();   // B2

  // ---------- phase G: gather qr = T[i][i-j+55] to regs; restage rB <- rkB ----------
  float qr_reg[2][4];
#pragma unroll
  for (int pass = 0; pass < 2; ++pass) {
    int i = pass * 32 + grp;
#pragma unroll
    for (int jt = 0; jt < 4; ++jt) {
      int j = jt * 16 + l16;
      qr_reg[pass][jt] = (i < 56 && j < 56) ? Tf[i * 113 + (i - j + 55)] : 0.f;
    }
  }
  {
    const int4v* rksrc = (const int4v*)((const short*)(prep + PF_RKP) + g * 4480);
    int4v* rbd = (int4v*)(SB + O_RB);
    for (int t = tid; t < 560; t += 512) rbd[t] = rksrc[t];
  }
  __syncthreads();   // B3

  // ---------- phase U: U = (kh+kl)@relk' MFMA -> UT f32 [111][57] transposed ----------
  float* UTf = (float*)SB;
  for (int tau = w; tau < 28; tau += 8) {
    int itT = tau / 7, ct = tau - itT * 7;
    bf16x8 av = *(bf16x8*)&SB[O_QKA + (itT * 16 + m) * 40 + qd * 8];
    bf16x8 bv = *(bf16x8*)&SB[O_RB + (ct * 16 + m) * 40 + qd * 8];
    f32x4 t0 = {0.f, 0.f, 0.f, 0.f};
    t0 = __builtin_amdgcn_mfma_f32_16x16x32_bf16(av, bv, t0, 0, 0, 0);
    int d = ct * 16 + m;
    if (d < 111) {
#pragma unroll
      for (int r = 0; r < 4; ++r) {
        int j2 = itT * 16 + qd * 4 + r;
        if (j2 < 56) UTf[d * 57 + j2] = t0[r];     // UT[d][j]
      }
    }
  }
  __syncthreads();   // B4

  // ---------- phase C: logits (qk VALU + qr reg + kr gather) + in-register softmax ----------
  float P[2][4];
  {
    const float* qkTf = (const float*)(SB + O_QKT);
    const float sh3 = s_sh3;
    float4 kv0[4], kv1[4];
#pragma unroll
    for (int jt = 0; jt < 4; ++jt) {
      int j = jt * 16 + l16;
      int jj = (j < 56) ? j : 0;
      kv0[jt] = *(const float4*)&qkTf[jj * 20 + 8];
      kv1[jt] = *(const float4*)&qkTf[jj * 20 + 12];
    }
#pragma unroll
    for (int pass = 0; pass < 2; ++pass) {
      int i = pass * 32 + grp;
      if (i < 56) {
        float4 qa = *(const float4*)&qkTf[i * 20 + 0];
        float4 qb4 = *(const float4*)&qkTf[i * 20 + 4];
        float L[4];
#pragma unroll
        for (int jt = 0; jt < 4; ++jt) {
          int j = jt * 16 + l16;
          if (j < 56) {
            float krv = UTf[(j - i + 55) * 57 + j];       // U[j][j-i+55]
            const float4 k0 = kv0[jt], k1 = kv1[jt];
            float acc = sh3 + qr_reg[pass][jt] + krv;
            acc = fmaf(qa.x, k0.x, acc);  acc = fmaf(qa.y, k0.y, acc);
            acc = fmaf(qa.z, k0.z, acc);  acc = fmaf(qa.w, k0.w, acc);
            acc = fmaf(qb4.x, k1.x, acc); acc = fmaf(qb4.y, k1.y, acc);
            acc = fmaf(qb4.z, k1.z, acc); acc = fmaf(qb4.w, k1.w, acc);
            L[jt] = acc;
          } else {
            L[jt] = -3.0e38f;
          }
        }
        float mx = fmaxf(fmaxf(L[0], L[1]), fmaxf(L[2], L[3]));
#pragma unroll
        for (int off = 1; off < 16; off <<= 1) mx = fmaxf(mx, __shfl_xor(mx, off));
        float sum = 0.f, ex[4];
#pragma unroll
        for (int jt = 0; jt < 4; ++jt) {
          ex[jt] = __expf(L[jt] - mx);
          sum += ex[jt];
        }
#pragma unroll
        for (int off = 1; off < 16; off <<= 1) sum += __shfl_xor(sum, off);
        float inv = 1.0f / sum;
#pragma unroll
        for (int jt = 0; jt < 4; ++jt) P[pass][jt] = ex[jt] * inv;
      }
    }
  }
  __syncthreads();   // B5 (T/UT & qkT reads complete)

  // ---------- phase S: scatter P -> simA/simShift (over dead UT); stage relv (over dead rB) ----------
  {
    const int4v z = {0, 0, 0, 0};
#pragma unroll
    for (int pass = 0; pass < 2; ++pass) {
      int i = pass * 32 + grp;                      // 0..63: all rows zeroed by owner
      if (l16 < 15) *(int4v*)&SB[O_SHFT + i * 120 + l16 * 8] = z;
      if (i < 56) {
#pragma unroll
        for (int jt = 0; jt < 4; ++jt) {
          int j = jt * 16 + l16;
          if (j < 56) {
            short pv = f2b(P[pass][jt]);
            SB[O_SIMA + i * 72 + j] = pv;                 // simA[i][j]
            SB[O_SHFT + i * 120 + (i - j + 55)] = pv;     // simShift[i][i-j+55]
          } else {
            SB[O_SIMA + i * 72 + j] = 0;                  // zero K-pad cols 56..63
          }
        }
      }
    }
    const int4v* rvp = (const int4v*)((const short*)(prep + PF_RV) + g * 2176);
    int4v* rvd = (int4v*)(SB + O_RELV);
    for (int t = tid; t < 272; t += 512) rvd[t] = rvp[t];
  }
  __syncthreads();   // B6

  // ---------- phase D: sv = P @ (vh+vl)^T (even waves), sve = relv @ simShift^T (odd) ----------
  f32x4 sveacc = {0.f, 0.f, 0.f, 0.f};
  {
    if (half == 0) {
      bf16x8 pa0 = *(bf16x8*)&SB[O_SIMA + (it * 16 + m) * 72 + qd * 8];
      bf16x8 pa1 = *(bf16x8*)&SB[O_SIMA + (it * 16 + m) * 72 + qd * 8 + 32];
      f32x4 acc = {0.f, 0.f, 0.f, 0.f};
      bf16x8 bv;
      bv = *(bf16x8*)&SB[O_VBH + m * 72 + qd * 8];
      acc = __builtin_amdgcn_mfma_f32_16x16x32_bf16(pa0, bv, acc, 0, 0, 0);
      bv = *(bf16x8*)&SB[O_VBH + m * 72 + qd * 8 + 32];
      acc = __builtin_amdgcn_mfma_f32_16x16x32_bf16(pa1, bv, acc, 0, 0, 0);
      bv = *(bf16x8*)&SB[O_VBL + m * 72 + qd * 8];
      acc = __builtin_amdgcn_mfma_f32_16x16x32_bf16(pa0, bv, acc, 0, 0, 0);
      bv = *(bf16x8*)&SB[O_VBL + m * 72 + qd * 8 + 32];
      acc = __builtin_amdgcn_mfma_f32_16x16x32_bf16(pa1, bv, acc, 0, 0, 0);
      float* svLf = (float*)(SB + O_SVL);
#pragma unroll
      for (int r = 0; r < 4; ++r) {
        int i2 = it * 16 + qd * 4 + r;
        if (i2 < 56) svLf[m * 60 + i2] = acc[r];   // svL[c=m][i]
      }
    } else {
#pragma unroll
      for (int ks = 0; ks < 4; ++ks) {
        bf16x8 av = *(bf16x8*)&SB[O_RELV + m * 136 + qd * 8 + ks * 32];
        bf16x8 bv = *(bf16x8*)&SB[O_SHFT + (it * 16 + m) * 120 + qd * 8 + ks * 32];
        sveacc = __builtin_amdgcn_mfma_f32_16x16x32_bf16(av, bv, sveacc, 0, 0, 0);
      }
    }
  }
  __syncthreads();   // B7

  // ---------- phase E: odd waves combine sv+sve with out-BN, store tmp ----------
  if (half == 1) {
    const int i2 = it * 16 + m;
    if (i2 < 56) {
      const float* svLf = (const float*)(SB + O_SVL);
#pragma unroll
      for (int r = 0; r < 4; ++r) {
        int c = qd * 4 + r;
        float svv = svLf[c * 60 + i2];
        float o = fmaf(svv, s_osc[2 * c], s_osh[2 * c]) +
                  fmaf(sveacc[r], s_osc[2 * c + 1], s_osh[2 * c + 1]);
        tmp[((size_t)b * 128 + g * 16 + c) * 56 + i2] = o;
      }
    }
  }
}

extern "C" void kernel_launch(void* const* d_in, const int* in_sizes, int n_in,
                              void* d_out, int out_size, void* d_ws, size_t ws_size,
                              hipStream_t stream) {
  const float* x   = (const float*)d_in[0];
  const float* wq  = (const float*)d_in[1];
  const float* rel = (const float*)d_in[2];
  const float* qg = (const float*)d_in[3];
  const float* qb = (const float*)d_in[4];
  const float* qm = (const float*)d_in[5];
  const float* qv = (const float*)d_in[6];
  const float* sg = (const float*)d_in[7];
  const float* sb = (const float*)d_in[8];
  const float* sm = (const float*)d_in[9];
  const float* sv = (const float*)d_in[10];
  const float* og = (const float*)d_in[11];
  const float* ob = (const float*)d_in[12];
  const float* om = (const float*)d_in[13];
  const float* ov = (const float*)d_in[14];
  float* out = (float*)d_out;

  float* tmp = (float*)d_ws;    // 25.7 MB

  k_prep<<<8, 256, 0, stream>>>(wq, rel, qg, qb, qm, qv,
                                sg, sb, sm, sv, og, ob, om, ov, out);
  k_transpose_in<<<896, 256, 0, stream>>>(x, (unsigned*)out);
  k_fused<<<7168, 512, 0, stream>>>((const short*)out, out, tmp);
  k_transpose_out<<<2048, 256, 0, stream>>>(tmp, out);
}

// Round 13
// 109.980 us; speedup vs baseline: 1.1614x; 1.1614x over previous
//
#include <hip/hip_runtime.h>
#include <hip/hip_bf16.h>
#include <cstddef>

#define EPSV 1e-5f

typedef __attribute__((ext_vector_type(8))) short bf16x8;
typedef __attribute__((ext_vector_type(4))) float f32x4;
typedef __attribute__((ext_vector_type(4))) short short4v;
typedef __attribute__((ext_vector_type(4))) int int4v;

__device__ __forceinline__ float b2f(short s) {
  union { unsigned u; float f; } x;
  x.u = ((unsigned)(unsigned short)s) << 16;
  return x.f;
}
__device__ __forceinline__ short f2b(float f) {
  union { __hip_bfloat16 h; short s; } x;
  x.h = __float2bfloat16(f);
  return x.s;
}

// ---- prep region layout (float offsets inside d_out) ----
// d_out floats: [0, 3211264) = xbT bf16 [896][56][128]  (as shorts)
// prep tail at 3,300,000 (transpose_out overwrites d_out last):
#define PF_W    3300000   // bf16 [8][32][128]  = 16384 f
#define PF_RQ   3316384   // f32  [8][112][12]  = 10752 f  (scB-prescaled, pads/row111 zero)
#define PF_RK   3327136   // f32  [8][112][12]  = 10752 f  ((scC/scA)-prescaled)
#define PF_RV   3337888   // bf16 [8][16][136]  = 8704 f   (zero-padded d>=111)
#define PF_QSC  3346592   // f32 [256]  (k-rows scA-folded)
#define PF_QSH  3346848   // f32 [256]
#define PF_OSC  3347104   // f32 [256]
#define PF_OSH  3347360   // f32 [256]
#define PF_SH3  3347616   // f32 [8]

// Merged: blocks 0..7 = block-invariant prep (per-g tables);
//         blocks 8..903 = x transpose (16,128,56,56) f32 -> xbT bf16 [896][56][128].
__global__ __launch_bounds__(256) void k_prep_tin(
    const float* __restrict__ x, const float* __restrict__ wq,
    const float* __restrict__ rel,
    const float* __restrict__ qg, const float* __restrict__ qb,
    const float* __restrict__ qm, const float* __restrict__ qv,
    const float* __restrict__ sg, const float* __restrict__ sb,
    const float* __restrict__ sm, const float* __restrict__ svar,
    const float* __restrict__ og, const float* __restrict__ ob,
    const float* __restrict__ om, const float* __restrict__ ov,
    float* __restrict__ prep) {
  __shared__ short t2[128 * 57];
  const int tid = threadIdx.x;

  if (blockIdx.x < 8) {
    const int g = blockIdx.x;
    const float scA = sg[g] * rsqrtf(svar[g] + EPSV);
    const float scB = sg[8 + g] * rsqrtf(svar[8 + g] + EPSV);
    const float scC = sg[16 + g] * rsqrtf(svar[16 + g] + EPSV);
    const float rCA = scC / scA;

    short* wb = (short*)(prep + PF_W) + g * 4096;
    for (int t = tid; t < 1024; t += 256) {
      int o = t >> 5, c0 = (t & 31) * 4;
      float4 wv = *(const float4*)&wq[g * 4096 + o * 128 + c0];
      short4v s4 = {f2b(wv.x), f2b(wv.y), f2b(wv.z), f2b(wv.w)};
      *(short4v*)&wb[o * 128 + c0] = s4;
    }
    float* rq = prep + PF_RQ + g * 1344;
    float* rk = prep + PF_RK + g * 1344;
    for (int t = tid; t < 1344; t += 256) {
      int d = t / 12, c = t - d * 12;
      rq[t] = (c < 8 && d < 111) ? rel[c * 111 + d] * scB : 0.f;
      rk[t] = (c < 8 && d < 111) ? rel[(8 + c) * 111 + d] * rCA : 0.f;
    }
    short* rv = (short*)(prep + PF_RV) + g * 2176;
    for (int t = tid; t < 2176; t += 256) {
      int c = t / 136, d = t - c * 136;
      rv[t] = (d < 111) ? f2b(rel[(16 + c) * 111 + d]) : (short)0;
    }
    if (tid < 32) {
      int ch = g * 32 + tid;
      float sc = qg[ch] * rsqrtf(qv[ch] + EPSV);
      float sh = qb[ch] - qm[ch] * sc;
      if (tid >= 8 && tid < 16) { sc *= scA; sh *= scA; }   // k' = scA * k_bn
      prep[PF_QSC + ch] = sc;
      prep[PF_QSH + ch] = sh;
      float so = og[ch] * rsqrtf(ov[ch] + EPSV);
      prep[PF_OSC + ch] = so;
      prep[PF_OSH + ch] = ob[ch] - om[ch] * so;
    }
    if (tid == 0) {
      float shA = sb[g] - sm[g] * scA;
      float shB = sb[8 + g] - sm[8 + g] * scB;
      float shC = sb[16 + g] - sm[16 + g] * scC;
      prep[PF_SH3 + g] = shA + shB + shC;
    }
  } else {
    const int nh = blockIdx.x - 8;          // n*56 + h
    const int n = nh / 56, h = nh - n * 56;
    unsigned* xbT = (unsigned*)prep;
    const float* src = x + (size_t)n * 401408 + h * 56;
    for (int t = tid; t < 1792; t += 256) {   // 128 c x 14 w-quads
      int c = t / 14, w4 = (t - c * 14) * 4;
      float4 v = *(const float4*)&src[c * 3136 + w4];
      t2[c * 57 + w4 + 0] = f2b(v.x);
      t2[c * 57 + w4 + 1] = f2b(v.y);
      t2[c * 57 + w4 + 2] = f2b(v.z);
      t2[c * 57 + w4 + 3] = f2b(v.w);
    }
    __syncthreads();
    for (int t = tid; t < 3584; t += 256) {   // 56 w x 64 c-pairs (u32)
      int w = t >> 6, cp = t & 63;
      unsigned lo = (unsigned short)t2[(2 * cp) * 57 + w];
      unsigned hi = (unsigned short)t2[(2 * cp + 1) * 57 + w];
      xbT[(((size_t)(n * 56 + w) * 56 + h) << 6) + cp] = lo | (hi << 16);
    }
  }
}

// tmp bf16 (896,128,56) -> out f32 (16,128,56,56): out[n][c][h][w] = tmp[n*56+w][c][h]
__global__ __launch_bounds__(256) void k_transpose_out(const short* __restrict__ tmp,
                                                       float* __restrict__ out) {
  int nc = blockIdx.x;
  int n = nc >> 7, c = nc & 127;
  __shared__ float t[56][57];
  for (int idx = threadIdx.x; idx < 3136; idx += 256) {
    int w = idx / 56, h = idx - w * 56;
    t[h][w] = b2f(tmp[((size_t)(n * 56 + w) * 128 + c) * 56 + h]);
  }
  __syncthreads();
  float* dst = out + (size_t)nc * 3136;
  for (int idx = threadIdx.x; idx < 3136; idx += 256)
    dst[idx] = t[idx / 56][idx % 56];
}

// LDS arena (offsets in shorts). Lifetime unions (identical to round 11):
//  [0,7680):      xsT bf16 [56][136] (A..B) | simShift bf16 [64][120] (C..D, row-owner zeroed)
//  [7680,12288):  Ws bf16 [32][136] (A..B)  | simA bf16 [64][72] (C..D)
//  [12288,14528): qkT f32 [56][20] (B..C) | svL f32 [16][60] (D..E)
//  [14528,17216): rqF f32 [112][12];  [17216,19904): rkF f32 [112][12]
//  [19904,22080): relv bf16 [16][136]
//  [22080,23232): VBH bf16 [16][72];  [23232,24384): VBL bf16 [16][72]
#define O_XST    0
#define O_SHFT   0
#define O_WS     7680
#define O_SIMA   7680
#define O_QKT    12288
#define O_SVL    12288
#define O_RQTF   14528
#define O_RKTF   17216
#define O_RELV   19904
#define O_VBH    22080
#define O_VBL    23232
#define SB_SH    24384

// One block per (b,g): bid = g*896 + b. LDS ~49.3 KB -> 3 blocks/CU.
__global__ __launch_bounds__(512) void k_fused(
    const short* __restrict__ xbT, const float* __restrict__ prep,
    short* __restrict__ tmp) {
  const int tid = threadIdx.x;
  const int g = blockIdx.x / 896;
  const int b = blockIdx.x - g * 896;

  __shared__ __align__(16) short SB[SB_SH];
  __shared__ float s_qsc[32], s_qsh[32], s_osc[32], s_osh[32], s_sh3;

  const int lane = tid & 63;
  const int w = tid >> 6;          // wave 0..7
  const int m = lane & 15;
  const int qd = lane >> 4;        // 0..3
  const int it = w >> 1;           // tile row group 0..3
  const int half = w & 1;
  const int grp = tid >> 4;        // 16-lane group 0..31
  const int l16 = tid & 15;

  // ---------- phase A: pure-copy staging ----------
  {
    int4v z = {0, 0, 0, 0};
    int4v* zp = (int4v*)(SB + O_VBH);                 // VBH+VBL = 2304 sh = 288 int4
    for (int i = tid; i < 288; i += 512) zp[i] = z;

    const short* xsrc = xbT + (size_t)b * 7168;       // [56][128] bf16
    for (int t = tid; t < 896; t += 512) {            // 56 rows x 16 chunks
      int h = t >> 4, ck = (t & 15) * 8;
      *(bf16x8*)&SB[O_XST + h * 136 + ck] = *(const bf16x8*)&xsrc[h * 128 + ck];
    }
    const short* wsrc = (const short*)(prep + PF_W) + g * 4096;
    for (int t = tid; t < 512; t += 512) {            // 32 rows x 16 chunks
      int o = t >> 4, ck = (t & 15) * 8;
      *(bf16x8*)&SB[O_WS + o * 136 + ck] = *(const bf16x8*)&wsrc[o * 128 + ck];
    }
    const f32x4* rqp = (const f32x4*)(prep + PF_RQ + g * 1344);
    const f32x4* rkp = (const f32x4*)(prep + PF_RK + g * 1344);
    f32x4* rqd = (f32x4*)(SB + O_RQTF);
    f32x4* rkd = (f32x4*)(SB + O_RKTF);
    for (int t = tid; t < 672; t += 512) {
      if (t < 336) rqd[t] = rqp[t];
      else         rkd[t - 336] = rkp[t - 336];
    }
    const int4v* rvp = (const int4v*)((const short*)(prep + PF_RV) + g * 2176);
    int4v* rvd = (int4v*)(SB + O_RELV);
    for (int t = tid; t < 272; t += 512) rvd[t] = rvp[t];
    if (tid < 32) {
      s_qsc[tid] = prep[PF_QSC + g * 32 + tid];
      s_qsh[tid] = prep[PF_QSH + g * 32 + tid];
      s_osc[tid] = prep[PF_OSC + g * 32 + tid];
      s_osh[tid] = prep[PF_OSH + g * 32 + tid];
    }
    if (tid == 0) s_sh3 = prep[PF_SH3 + g];
  }
  __syncthreads();   // B0

  // ---------- phase B: qkv = BN(W @ x) via MFMA; q,k' -> qkT f32 (float4), v -> VBH/VBL ----------
  {
    const int o = half * 16 + m;
    const int h = it * 16 + m;
    f32x4 acc = {0.f, 0.f, 0.f, 0.f};
    __builtin_amdgcn_s_setprio(1);
#pragma unroll
    for (int ks = 0; ks < 4; ++ks) {
      bf16x8 av = *(bf16x8*)&SB[O_WS + o * 136 + qd * 8 + ks * 32];
      bf16x8 bv = *(bf16x8*)&SB[O_XST + h * 136 + qd * 8 + ks * 32];
      acc = __builtin_amdgcn_mfma_f32_16x16x32_bf16(av, bv, acc, 0, 0, 0);
    }
    __builtin_amdgcn_s_setprio(0);
    if (h < 56) {                    // D col = h; D row = oo = half*16+qd*4+r
      float* qkTf = (float*)(SB + O_QKT);
      if (half == 0) {               // all 4 rows are q/k' -> one float4 store
        float4 o4;
        o4.x = fmaf(acc[0], s_qsc[qd * 4 + 0], s_qsh[qd * 4 + 0]);
        o4.y = fmaf(acc[1], s_qsc[qd * 4 + 1], s_qsh[qd * 4 + 1]);
        o4.z = fmaf(acc[2], s_qsc[qd * 4 + 2], s_qsh[qd * 4 + 2]);
        o4.w = fmaf(acc[3], s_qsc[qd * 4 + 3], s_qsh[qd * 4 + 3]);
        *(float4*)&qkTf[h * 20 + qd * 4] = o4;
      } else {                       // all 4 rows are v -> hi/lo bf16
#pragma unroll
        for (int r = 0; r < 4; ++r) {
          int cv = qd * 4 + r;
          float val = fmaf(acc[r], s_qsc[16 + cv], s_qsh[16 + cv]);
          short vh = f2b(val);
          short vl = f2b(val - b2f(vh));
          SB[O_VBH + cv * 72 + h] = vh;
          SB[O_VBL + cv * 72 + h] = vl;
        }
      }
    }
  }
  __syncthreads();   // B1

  // ---------- phase C: row-zero simShift + logits + in-register softmax + scatter ----------
  {
    const float* qkTf = (const float*)(SB + O_QKT);
    const float* rqf = (const float*)(SB + O_RQTF);
    const float* rkf = (const float*)(SB + O_RKTF);
    const float sh3 = s_sh3;
    const int4v z = {0, 0, 0, 0};

    // hoist k' (depends on l16/jt only)
    float4 kv0[4], kv1[4];
#pragma unroll
    for (int jt = 0; jt < 4; ++jt) {
      int j = jt * 16 + l16;
      int jj = (j < 56) ? j : 0;
      kv0[jt] = *(const float4*)&qkTf[jj * 20 + 8];
      kv1[jt] = *(const float4*)&qkTf[jj * 20 + 12];
    }

#pragma unroll
    for (int pass = 0; pass < 2; ++pass) {
      int i = pass * 32 + grp;
      // zero this group's simShift row (program order within wave: zero precedes scatter)
      if (i < 64 && l16 < 15) *(int4v*)&SB[O_SHFT + i * 120 + l16 * 8] = z;
      if (i < 56) {
        float4 qa = *(const float4*)&qkTf[i * 20 + 0];
        float4 qb4 = *(const float4*)&qkTf[i * 20 + 4];
        float L[4];
#pragma unroll
        for (int jt = 0; jt < 4; ++jt) {
          int j = jt * 16 + l16;
          if (j < 56) {
            const float4 rq0 = *(const float4*)&rqf[(i - j + 55) * 12];
            const float4 rq1 = *(const float4*)&rqf[(i - j + 55) * 12 + 4];
            const float4 rk0 = *(const float4*)&rkf[(j - i + 55) * 12];
            const float4 rk1 = *(const float4*)&rkf[(j - i + 55) * 12 + 4];
            const float4 k0 = kv0[jt], k1 = kv1[jt];
            float acc = sh3;
            acc = fmaf(qa.x, k0.x, acc);  acc = fmaf(qa.y, k0.y, acc);
            acc = fmaf(qa.z, k0.z, acc);  acc = fmaf(qa.w, k0.w, acc);
            acc = fmaf(qb4.x, k1.x, acc); acc = fmaf(qb4.y, k1.y, acc);
            acc = fmaf(qb4.z, k1.z, acc); acc = fmaf(qb4.w, k1.w, acc);
            acc = fmaf(qa.x, rq0.x, acc);  acc = fmaf(qa.y, rq0.y, acc);
            acc = fmaf(qa.z, rq0.z, acc);  acc = fmaf(qa.w, rq0.w, acc);
            acc = fmaf(qb4.x, rq1.x, acc); acc = fmaf(qb4.y, rq1.y, acc);
            acc = fmaf(qb4.z, rq1.z, acc); acc = fmaf(qb4.w, rq1.w, acc);
            acc = fmaf(k0.x, rk0.x, acc);  acc = fmaf(k0.y, rk0.y, acc);
            acc = fmaf(k0.z, rk0.z, acc);  acc = fmaf(k0.w, rk0.w, acc);
            acc = fmaf(k1.x, rk1.x, acc);  acc = fmaf(k1.y, rk1.y, acc);
            acc = fmaf(k1.w, rk1.w, acc);  acc = fmaf(k1.z, rk1.z, acc);
            L[jt] = acc;
          } else {
            L[jt] = -3.0e38f;
          }
        }
        float mx = fmaxf(fmaxf(L[0], L[1]), fmaxf(L[2], L[3]));
#pragma unroll
        for (int off = 1; off < 16; off <<= 1) mx = fmaxf(mx, __shfl_xor(mx, off));
        float sum = 0.f, ex[4];
#pragma unroll
        for (int jt = 0; jt < 4; ++jt) {
          ex[jt] = __expf(L[jt] - mx);
          sum += ex[jt];
        }
#pragma unroll
        for (int off = 1; off < 16; off <<= 1) sum += __shfl_xor(sum, off);
        float inv = 1.0f / sum;
#pragma unroll
        for (int jt = 0; jt < 4; ++jt) {
          int j = jt * 16 + l16;
          if (j < 56) {
            short pv = f2b(ex[jt] * inv);
            SB[O_SIMA + i * 72 + j] = pv;                 // simA[i][j]
            SB[O_SHFT + i * 120 + (i - j + 55)] = pv;     // simShift[i][i-j+55]
          } else {
            SB[O_SIMA + i * 72 + j] = 0;                  // zero cols 56..63 (K-pad)
          }
        }
      }
    }
  }
  __syncthreads();   // B3

  // ---------- phase D: sv = P @ (vh+vl)^T (even waves), sve = relv @ simShift^T (odd) ----------
  f32x4 sveacc = {0.f, 0.f, 0.f, 0.f};
  {
    if (half == 0) {
      bf16x8 pa0 = *(bf16x8*)&SB[O_SIMA + (it * 16 + m) * 72 + qd * 8];
      bf16x8 pa1 = *(bf16x8*)&SB[O_SIMA + (it * 16 + m) * 72 + qd * 8 + 32];
      f32x4 acc = {0.f, 0.f, 0.f, 0.f};
      bf16x8 bv;
      __builtin_amdgcn_s_setprio(1);
      bv = *(bf16x8*)&SB[O_VBH + m * 72 + qd * 8];
      acc = __builtin_amdgcn_mfma_f32_16x16x32_bf16(pa0, bv, acc, 0, 0, 0);
      bv = *(bf16x8*)&SB[O_VBH + m * 72 + qd * 8 + 32];
      acc = __builtin_amdgcn_mfma_f32_16x16x32_bf16(pa1, bv, acc, 0, 0, 0);
      bv = *(bf16x8*)&SB[O_VBL + m * 72 + qd * 8];
      acc = __builtin_amdgcn_mfma_f32_16x16x32_bf16(pa0, bv, acc, 0, 0, 0);
      bv = *(bf16x8*)&SB[O_VBL + m * 72 + qd * 8 + 32];
      acc = __builtin_amdgcn_mfma_f32_16x16x32_bf16(pa1, bv, acc, 0, 0, 0);
      __builtin_amdgcn_s_setprio(0);
      float* svLf = (float*)(SB + O_SVL);
#pragma unroll
      for (int r = 0; r < 4; ++r) {
        int i2 = it * 16 + qd * 4 + r;             // D row = i
        if (i2 < 56) svLf[m * 60 + i2] = acc[r];   // svL[c=m][i]
      }
    } else {
      __builtin_amdgcn_s_setprio(1);
#pragma unroll
      for (int ks = 0; ks < 4; ++ks) {
        bf16x8 av = *(bf16x8*)&SB[O_RELV + m * 136 + qd * 8 + ks * 32];
        bf16x8 bv = *(bf16x8*)&SB[O_SHFT + (it * 16 + m) * 120 + qd * 8 + ks * 32];
        sveacc = __builtin_amdgcn_mfma_f32_16x16x32_bf16(av, bv, sveacc, 0, 0, 0);
      }
      __builtin_amdgcn_s_setprio(0);
      // sveacc[r] = sve[c=qd*4+r][i=it*16+m]
    }
  }
  __syncthreads();   // B4

  // ---------- phase E: odd waves combine sv+sve with out-BN, store tmp (bf16) ----------
  if (half == 1) {
    const int i2 = it * 16 + m;
    if (i2 < 56) {
      const float* svLf = (const float*)(SB + O_SVL);
#pragma unroll
      for (int r = 0; r < 4; ++r) {
        int c = qd * 4 + r;
        float svv = svLf[c * 60 + i2];
        float o = fmaf(svv, s_osc[2 * c], s_osh[2 * c]) +
                  fmaf(sveacc[r], s_osc[2 * c + 1], s_osh[2 * c + 1]);
        tmp[((size_t)b * 128 + g * 16 + c) * 56 + i2] = f2b(o);
      }
    }
  }
}

extern "C" void kernel_launch(void* const* d_in, const int* in_sizes, int n_in,
                              void* d_out, int out_size, void* d_ws, size_t ws_size,
                              hipStream_t stream) {
  const float* x   = (const float*)d_in[0];
  const float* wq  = (const float*)d_in[1];
  const float* rel = (const float*)d_in[2];
  const float* qg = (const float*)d_in[3];
  const float* qb = (const float*)d_in[4];
  const float* qm = (const float*)d_in[5];
  const float* qv = (const float*)d_in[6];
  const float* sg = (const float*)d_in[7];
  const float* sb = (const float*)d_in[8];
  const float* sm = (const float*)d_in[9];
  const float* sv = (const float*)d_in[10];
  const float* og = (const float*)d_in[11];
  const float* ob = (const float*)d_in[12];
  const float* om = (const float*)d_in[13];
  const float* ov = (const float*)d_in[14];
  float* out = (float*)d_out;

  // d_out doubles as staging: xbT bf16 [0,12.8MB) + prep tables at 13.2MB.
  // Both fully consumed before k_transpose_out overwrites d_out.
  short* tmp = (short*)d_ws;    // bf16 tmp, 12.8 MB

  k_prep_tin<<<904, 256, 0, stream>>>(x, wq, rel, qg, qb, qm, qv,
                                      sg, sb, sm, sv, og, ob, om, ov, out);
  k_fused<<<7168, 512, 0, stream>>>((const short*)out, out, tmp);
  k_transpose_out<<<2048, 256, 0, stream>>>(tmp, out);
}

// Round 14
// 109.300 us; speedup vs baseline: 1.1686x; 1.0062x over previous
//
#include <hip/hip_runtime.h>
#include <hip/hip_bf16.h>
#include <cstddef>

#define EPSV 1e-5f

typedef __attribute__((ext_vector_type(8))) short bf16x8;
typedef __attribute__((ext_vector_type(4))) float f32x4;
typedef __attribute__((ext_vector_type(2))) float f32x2;
typedef __attribute__((ext_vector_type(4))) short short4v;
typedef __attribute__((ext_vector_type(4))) int int4v;

__device__ __forceinline__ float b2f(short s) {
  union { unsigned u; float f; } x;
  x.u = ((unsigned)(unsigned short)s) << 16;
  return x.f;
}
__device__ __forceinline__ short f2b(float f) {
  union { __hip_bfloat16 h; short s; } x;
  x.h = __float2bfloat16(f);
  return x.s;
}
__device__ __forceinline__ f32x2 lo2(f32x4 v) { return __builtin_shufflevector(v, v, 0, 1); }
__device__ __forceinline__ f32x2 hi2(f32x4 v) { return __builtin_shufflevector(v, v, 2, 3); }
__device__ __forceinline__ f32x2 pkfma(f32x2 a, f32x2 b, f32x2 c) {
#if __has_builtin(__builtin_elementwise_fma)
  return __builtin_elementwise_fma(a, b, c);   // -> v_pk_fma_f32 on CDNA
#else
  f32x2 d; d[0] = fmaf(a[0], b[0], c[0]); d[1] = fmaf(a[1], b[1], c[1]); return d;
#endif
}

// ---- prep region layout (float offsets inside d_out) ----
// d_out floats: [0, 3211264) = xbT bf16 [896][56][128]  (as shorts)
// prep tail at 3,300,000 (transpose_out overwrites d_out last):
#define PF_W    3300000   // bf16 [8][32][128]  = 16384 f
#define PF_RQ   3316384   // f32  [8][112][12]  = 10752 f  (scB-prescaled, pads/row111 zero)
#define PF_RK   3327136   // f32  [8][112][12]  = 10752 f  ((scC/scA)-prescaled)
#define PF_RV   3337888   // bf16 [8][16][136]  = 8704 f   (zero-padded d>=111)
#define PF_QSC  3346592   // f32 [256]  (k-rows scA-folded)
#define PF_QSH  3346848   // f32 [256]
#define PF_OSC  3347104   // f32 [256]
#define PF_OSH  3347360   // f32 [256]
#define PF_SH3  3347616   // f32 [8]

// Merged: blocks 0..7 = block-invariant prep (per-g tables);
//         blocks 8..903 = x transpose (16,128,56,56) f32 -> xbT bf16 [896][56][128].
__global__ __launch_bounds__(256) void k_prep_tin(
    const float* __restrict__ x, const float* __restrict__ wq,
    const float* __restrict__ rel,
    const float* __restrict__ qg, const float* __restrict__ qb,
    const float* __restrict__ qm, const float* __restrict__ qv,
    const float* __restrict__ sg, const float* __restrict__ sb,
    const float* __restrict__ sm, const float* __restrict__ svar,
    const float* __restrict__ og, const float* __restrict__ ob,
    const float* __restrict__ om, const float* __restrict__ ov,
    float* __restrict__ prep) {
  __shared__ short t2[128 * 57];
  const int tid = threadIdx.x;

  if (blockIdx.x < 8) {
    const int g = blockIdx.x;
    const float scA = sg[g] * rsqrtf(svar[g] + EPSV);
    const float scB = sg[8 + g] * rsqrtf(svar[8 + g] + EPSV);
    const float scC = sg[16 + g] * rsqrtf(svar[16 + g] + EPSV);
    const float rCA = scC / scA;

    short* wb = (short*)(prep + PF_W) + g * 4096;
    for (int t = tid; t < 1024; t += 256) {
      int o = t >> 5, c0 = (t & 31) * 4;
      float4 wv = *(const float4*)&wq[g * 4096 + o * 128 + c0];
      short4v s4 = {f2b(wv.x), f2b(wv.y), f2b(wv.z), f2b(wv.w)};
      *(short4v*)&wb[o * 128 + c0] = s4;
    }
    float* rq = prep + PF_RQ + g * 1344;
    float* rk = prep + PF_RK + g * 1344;
    for (int t = tid; t < 1344; t += 256) {
      int d = t / 12, c = t - d * 12;
      rq[t] = (c < 8 && d < 111) ? rel[c * 111 + d] * scB : 0.f;
      rk[t] = (c < 8 && d < 111) ? rel[(8 + c) * 111 + d] * rCA : 0.f;
    }
    short* rv = (short*)(prep + PF_RV) + g * 2176;
    for (int t = tid; t < 2176; t += 256) {
      int c = t / 136, d = t - c * 136;
      rv[t] = (d < 111) ? f2b(rel[(16 + c) * 111 + d]) : (short)0;
    }
    if (tid < 32) {
      int ch = g * 32 + tid;
      float sc = qg[ch] * rsqrtf(qv[ch] + EPSV);
      float sh = qb[ch] - qm[ch] * sc;
      if (tid >= 8 && tid < 16) { sc *= scA; sh *= scA; }   // k' = scA * k_bn
      prep[PF_QSC + ch] = sc;
      prep[PF_QSH + ch] = sh;
      float so = og[ch] * rsqrtf(ov[ch] + EPSV);
      prep[PF_OSC + ch] = so;
      prep[PF_OSH + ch] = ob[ch] - om[ch] * so;
    }
    if (tid == 0) {
      float shA = sb[g] - sm[g] * scA;
      float shB = sb[8 + g] - sm[8 + g] * scB;
      float shC = sb[16 + g] - sm[16 + g] * scC;
      prep[PF_SH3 + g] = shA + shB + shC;
    }
  } else {
    const int nh = blockIdx.x - 8;          // n*56 + h
    const int n = nh / 56, h = nh - n * 56;
    unsigned* xbT = (unsigned*)prep;
    const float* src = x + (size_t)n * 401408 + h * 56;
    for (int t = tid; t < 1792; t += 256) {   // 128 c x 14 w-quads
      int c = t / 14, w4 = (t - c * 14) * 4;
      float4 v = *(const float4*)&src[c * 3136 + w4];
      t2[c * 57 + w4 + 0] = f2b(v.x);
      t2[c * 57 + w4 + 1] = f2b(v.y);
      t2[c * 57 + w4 + 2] = f2b(v.z);
      t2[c * 57 + w4 + 3] = f2b(v.w);
    }
    __syncthreads();
    for (int t = tid; t < 3584; t += 256) {   // 56 w x 64 c-pairs (u32)
      int w = t >> 6, cp = t & 63;
      unsigned lo = (unsigned short)t2[(2 * cp) * 57 + w];
      unsigned hi = (unsigned short)t2[(2 * cp + 1) * 57 + w];
      xbT[(((size_t)(n * 56 + w) * 56 + h) << 6) + cp] = lo | (hi << 16);
    }
  }
}

// tmp bf16 (896,128,56) -> out f32 (16,128,56,56): out[n][c][h][w] = tmp[n*56+w][c][h]
__global__ __launch_bounds__(256) void k_transpose_out(const short* __restrict__ tmp,
                                                       float* __restrict__ out) {
  int nc = blockIdx.x;
  int n = nc >> 7, c = nc & 127;
  __shared__ float t[56][57];
  for (int idx = threadIdx.x; idx < 3136; idx += 256) {
    int w = idx / 56, h = idx - w * 56;
    t[h][w] = b2f(tmp[((size_t)(n * 56 + w) * 128 + c) * 56 + h]);
  }
  __syncthreads();
  float* dst = out + (size_t)nc * 3136;
  for (int idx = threadIdx.x; idx < 3136; idx += 256)
    dst[idx] = t[idx / 56][idx % 56];
}

// LDS arena (offsets in shorts). Lifetime unions (identical to round 11/13):
//  [0,7680):      xsT bf16 [56][136] (A..B) | simShift bf16 [64][120] (C..D, row-owner zeroed)
//  [7680,12288):  Ws bf16 [32][136] (A..B)  | simA bf16 [64][72] (C..D)
//  [12288,14528): qkT f32 [56][20] (B..C) | svL f32 [16][60] (D..E)
//  [14528,17216): rqF f32 [112][12];  [17216,19904): rkF f32 [112][12]
//  [19904,22080): relv bf16 [16][136]
//  [22080,23232): VBH bf16 [16][72];  [23232,24384): VBL bf16 [16][72]
#define O_XST    0
#define O_SHFT   0
#define O_WS     7680
#define O_SIMA   7680
#define O_QKT    12288
#define O_SVL    12288
#define O_RQTF   14528
#define O_RKTF   17216
#define O_RELV   19904
#define O_VBH    22080
#define O_VBL    23232
#define SB_SH    24384

// One block per (b,g): bid = g*896 + b. LDS ~49.3 KB -> 3 blocks/CU.
__global__ __launch_bounds__(512) void k_fused(
    const short* __restrict__ xbT, const float* __restrict__ prep,
    short* __restrict__ tmp) {
  const int tid = threadIdx.x;
  const int g = blockIdx.x / 896;
  const int b = blockIdx.x - g * 896;

  __shared__ __align__(16) short SB[SB_SH];
  __shared__ float s_qsc[32], s_qsh[32], s_osc[32], s_osh[32], s_sh3;

  const int lane = tid & 63;
  const int w = tid >> 6;          // wave 0..7
  const int m = lane & 15;
  const int qd = lane >> 4;        // 0..3
  const int it = w >> 1;           // tile row group 0..3
  const int half = w & 1;
  const int grp = tid >> 4;        // 16-lane group 0..31
  const int l16 = tid & 15;

  // ---------- phase A: pure-copy staging ----------
  {
    int4v z = {0, 0, 0, 0};
    int4v* zp = (int4v*)(SB + O_VBH);                 // VBH+VBL = 2304 sh = 288 int4
    for (int i = tid; i < 288; i += 512) zp[i] = z;

    const short* xsrc = xbT + (size_t)b * 7168;       // [56][128] bf16
    for (int t = tid; t < 896; t += 512) {            // 56 rows x 16 chunks
      int h = t >> 4, ck = (t & 15) * 8;
      *(bf16x8*)&SB[O_XST + h * 136 + ck] = *(const bf16x8*)&xsrc[h * 128 + ck];
    }
    const short* wsrc = (const short*)(prep + PF_W) + g * 4096;
    for (int t = tid; t < 512; t += 512) {            // 32 rows x 16 chunks
      int o = t >> 4, ck = (t & 15) * 8;
      *(bf16x8*)&SB[O_WS + o * 136 + ck] = *(const bf16x8*)&wsrc[o * 128 + ck];
    }
    const f32x4* rqp = (const f32x4*)(prep + PF_RQ + g * 1344);
    const f32x4* rkp = (const f32x4*)(prep + PF_RK + g * 1344);
    f32x4* rqd = (f32x4*)(SB + O_RQTF);
    f32x4* rkd = (f32x4*)(SB + O_RKTF);
    for (int t = tid; t < 672; t += 512) {
      if (t < 336) rqd[t] = rqp[t];
      else         rkd[t - 336] = rkp[t - 336];
    }
    const int4v* rvp = (const int4v*)((const short*)(prep + PF_RV) + g * 2176);
    int4v* rvd = (int4v*)(SB + O_RELV);
    for (int t = tid; t < 272; t += 512) rvd[t] = rvp[t];
    if (tid < 32) {
      s_qsc[tid] = prep[PF_QSC + g * 32 + tid];
      s_qsh[tid] = prep[PF_QSH + g * 32 + tid];
      s_osc[tid] = prep[PF_OSC + g * 32 + tid];
      s_osh[tid] = prep[PF_OSH + g * 32 + tid];
    }
    if (tid == 0) s_sh3 = prep[PF_SH3 + g];
  }
  __syncthreads();   // B0

  // ---------- phase B: qkv = BN(W @ x) via MFMA; q,k' -> qkT f32 (float4), v -> VBH/VBL ----------
  {
    const int o = half * 16 + m;
    const int h = it * 16 + m;
    f32x4 acc = {0.f, 0.f, 0.f, 0.f};
    __builtin_amdgcn_s_setprio(1);
#pragma unroll
    for (int ks = 0; ks < 4; ++ks) {
      bf16x8 av = *(bf16x8*)&SB[O_WS + o * 136 + qd * 8 + ks * 32];
      bf16x8 bv = *(bf16x8*)&SB[O_XST + h * 136 + qd * 8 + ks * 32];
      acc = __builtin_amdgcn_mfma_f32_16x16x32_bf16(av, bv, acc, 0, 0, 0);
    }
    __builtin_amdgcn_s_setprio(0);
    if (h < 56) {                    // D col = h; D row = oo = half*16+qd*4+r
      float* qkTf = (float*)(SB + O_QKT);
      if (half == 0) {               // all 4 rows are q/k' -> one float4 store
        float4 o4;
        o4.x = fmaf(acc[0], s_qsc[qd * 4 + 0], s_qsh[qd * 4 + 0]);
        o4.y = fmaf(acc[1], s_qsc[qd * 4 + 1], s_qsh[qd * 4 + 1]);
        o4.z = fmaf(acc[2], s_qsc[qd * 4 + 2], s_qsh[qd * 4 + 2]);
        o4.w = fmaf(acc[3], s_qsc[qd * 4 + 3], s_qsh[qd * 4 + 3]);
        *(float4*)&qkTf[h * 20 + qd * 4] = o4;
      } else {                       // all 4 rows are v -> hi/lo bf16
#pragma unroll
        for (int r = 0; r < 4; ++r) {
          int cv = qd * 4 + r;
          float val = fmaf(acc[r], s_qsc[16 + cv], s_qsh[16 + cv]);
          short vh = f2b(val);
          short vl = f2b(val - b2f(vh));
          SB[O_VBH + cv * 72 + h] = vh;
          SB[O_VBL + cv * 72 + h] = vl;
        }
      }
    }
  }
  __syncthreads();   // B1

  // ---------- phase C: row-zero simShift + logits (v_pk_fma_f32) + softmax + scatter ----------
  {
    const float* qkTf = (const float*)(SB + O_QKT);
    const float* rqf = (const float*)(SB + O_RQTF);
    const float* rkf = (const float*)(SB + O_RKTF);
    const float sh3 = s_sh3;
    const int4v z = {0, 0, 0, 0};

    // hoist k' (depends on l16/jt only)
    f32x4 kv0[4], kv1[4];
#pragma unroll
    for (int jt = 0; jt < 4; ++jt) {
      int j = jt * 16 + l16;
      int jj = (j < 56) ? j : 0;
      kv0[jt] = *(const f32x4*)&qkTf[jj * 20 + 8];
      kv1[jt] = *(const f32x4*)&qkTf[jj * 20 + 12];
    }

#pragma unroll
    for (int pass = 0; pass < 2; ++pass) {
      int i = pass * 32 + grp;
      // zero this group's simShift row (program order within wave: zero precedes scatter)
      if (i < 64 && l16 < 15) *(int4v*)&SB[O_SHFT + i * 120 + l16 * 8] = z;
      if (i < 56) {
        f32x4 qa4 = *(const f32x4*)&qkTf[i * 20 + 0];
        f32x4 qb4 = *(const f32x4*)&qkTf[i * 20 + 4];
        const f32x2 qlo = lo2(qa4), qhi = hi2(qa4);
        const f32x2 rlo = lo2(qb4), rhi = hi2(qb4);
        float L[4];
#pragma unroll
        for (int jt = 0; jt < 4; ++jt) {
          int j = jt * 16 + l16;
          if (j < 56) {
            const f32x4 rq0 = *(const f32x4*)&rqf[(i - j + 55) * 12];
            const f32x4 rq1 = *(const f32x4*)&rqf[(i - j + 55) * 12 + 4];
            const f32x4 rk0 = *(const f32x4*)&rkf[(j - i + 55) * 12];
            const f32x4 rk1 = *(const f32x4*)&rkf[(j - i + 55) * 12 + 4];
            const f32x4 k0 = kv0[jt], k1 = kv1[jt];
            f32x2 acc2 = {sh3, 0.f};
            acc2 = pkfma(qlo, lo2(k0), acc2);
            acc2 = pkfma(qhi, hi2(k0), acc2);
            acc2 = pkfma(rlo, lo2(k1), acc2);
            acc2 = pkfma(rhi, hi2(k1), acc2);
            acc2 = pkfma(qlo, lo2(rq0), acc2);
            acc2 = pkfma(qhi, hi2(rq0), acc2);
            acc2 = pkfma(rlo, lo2(rq1), acc2);
            acc2 = pkfma(rhi, hi2(rq1), acc2);
            acc2 = pkfma(lo2(k0), lo2(rk0), acc2);
            acc2 = pkfma(hi2(k0), hi2(rk0), acc2);
            acc2 = pkfma(lo2(k1), lo2(rk1), acc2);
            acc2 = pkfma(hi2(k1), hi2(rk1), acc2);
            L[jt] = acc2[0] + acc2[1];
          } else {
            L[jt] = -3.0e38f;
          }
        }
        float mx = fmaxf(fmaxf(L[0], L[1]), fmaxf(L[2], L[3]));
#pragma unroll
        for (int off = 1; off < 16; off <<= 1) mx = fmaxf(mx, __shfl_xor(mx, off));
        float sum = 0.f, ex[4];
#pragma unroll
        for (int jt = 0; jt < 4; ++jt) {
          ex[jt] = __expf(L[jt] - mx);
          sum += ex[jt];
        }
#pragma unroll
        for (int off = 1; off < 16; off <<= 1) sum += __shfl_xor(sum, off);
        float inv = 1.0f / sum;
#pragma unroll
        for (int jt = 0; jt < 4; ++jt) {
          int j = jt * 16 + l16;
          if (j < 56) {
            short pv = f2b(ex[jt] * inv);
            SB[O_SIMA + i * 72 + j] = pv;                 // simA[i][j]
            SB[O_SHFT + i * 120 + (i - j + 55)] = pv;     // simShift[i][i-j+55]
          } else {
            SB[O_SIMA + i * 72 + j] = 0;                  // zero cols 56..63 (K-pad)
          }
        }
      }
    }
  }
  __syncthreads();   // B3

  // ---------- phase D: sv = P @ (vh+vl)^T (even waves), sve = relv @ simShift^T (odd) ----------
  f32x4 sveacc = {0.f, 0.f, 0.f, 0.f};
  {
    if (half == 0) {
      bf16x8 pa0 = *(bf16x8*)&SB[O_SIMA + (it * 16 + m) * 72 + qd * 8];
      bf16x8 pa1 = *(bf16x8*)&SB[O_SIMA + (it * 16 + m) * 72 + qd * 8 + 32];
      f32x4 acc = {0.f, 0.f, 0.f, 0.f};
      bf16x8 bv;
      __builtin_amdgcn_s_setprio(1);
      bv = *(bf16x8*)&SB[O_VBH + m * 72 + qd * 8];
      acc = __builtin_amdgcn_mfma_f32_16x16x32_bf16(pa0, bv, acc, 0, 0, 0);
      bv = *(bf16x8*)&SB[O_VBH + m * 72 + qd * 8 + 32];
      acc = __builtin_amdgcn_mfma_f32_16x16x32_bf16(pa1, bv, acc, 0, 0, 0);
      bv = *(bf16x8*)&SB[O_VBL + m * 72 + qd * 8];
      acc = __builtin_amdgcn_mfma_f32_16x16x32_bf16(pa0, bv, acc, 0, 0, 0);
      bv = *(bf16x8*)&SB[O_VBL + m * 72 + qd * 8 + 32];
      acc = __builtin_amdgcn_mfma_f32_16x16x32_bf16(pa1, bv, acc, 0, 0, 0);
      __builtin_amdgcn_s_setprio(0);
      float* svLf = (float*)(SB + O_SVL);
#pragma unroll
      for (int r = 0; r < 4; ++r) {
        int i2 = it * 16 + qd * 4 + r;             // D row = i
        if (i2 < 56) svLf[m * 60 + i2] = acc[r];   // svL[c=m][i]
      }
    } else {
      __builtin_amdgcn_s_setprio(1);
#pragma unroll
      for (int ks = 0; ks < 4; ++ks) {
        bf16x8 av = *(bf16x8*)&SB[O_RELV + m * 136 + qd * 8 + ks * 32];
        bf16x8 bv = *(bf16x8*)&SB[O_SHFT + (it * 16 + m) * 120 + qd * 8 + ks * 32];
        sveacc = __builtin_amdgcn_mfma_f32_16x16x32_bf16(av, bv, sveacc, 0, 0, 0);
      }
      __builtin_amdgcn_s_setprio(0);
      // sveacc[r] = sve[c=qd*4+r][i=it*16+m]
    }
  }
  __syncthreads();   // B4

  // ---------- phase E: odd waves combine sv+sve with out-BN, store tmp (bf16) ----------
  if (half == 1) {
    const int i2 = it * 16 + m;
    if (i2 < 56) {
      const float* svLf = (const float*)(SB + O_SVL);
#pragma unroll
      for (int r = 0; r < 4; ++r) {
        int c = qd * 4 + r;
        float svv = svLf[c * 60 + i2];
        float o = fmaf(svv, s_osc[2 * c], s_osh[2 * c]) +
                  fmaf(sveacc[r], s_osc[2 * c + 1], s_osh[2 * c + 1]);
        tmp[((size_t)b * 128 + g * 16 + c) * 56 + i2] = f2b(o);
      }
    }
  }
}

extern "C" void kernel_launch(void* const* d_in, const int* in_sizes, int n_in,
                              void* d_out, int out_size, void* d_ws, size_t ws_size,
                              hipStream_t stream) {
  const float* x   = (const float*)d_in[0];
  const float* wq  = (const float*)d_in[1];
  const float* rel = (const float*)d_in[2];
  const float* qg = (const float*)d_in[3];
  const float* qb = (const float*)d_in[4];
  const float* qm = (const float*)d_in[5];
  const float* qv = (const float*)d_in[6];
  const float* sg = (const float*)d_in[7];
  const float* sb = (const float*)d_in[8];
  const float* sm = (const float*)d_in[9];
  const float* sv = (const float*)d_in[10];
  const float* og = (const float*)d_in[11];
  const float* ob = (const float*)d_in[12];
  const float* om = (const float*)d_in[13];
  const float* ov = (const float*)d_in[14];
  float* out = (float*)d_out;

  // d_out doubles as staging: xbT bf16 [0,12.8MB) + prep tables at 13.2MB.
  // Both fully consumed before k_transpose_out overwrites d_out.
  short* tmp = (short*)d_ws;    // bf16 tmp, 12.8 MB

  k_prep_tin<<<904, 256, 0, stream>>>(x, wq, rel, qg, qb, qm, qv,
                                      sg, sb, sm, sv, og, ob, om, ov, out);
  k_fused<<<7168, 512, 0, stream>>>((const short*)out, out, tmp);
  k_transpose_out<<<2048, 256, 0, stream>>>(tmp, out);
}

// Round 17
// 100.466 us; speedup vs baseline: 1.2714x; 1.0879x over previous
//
#include <hip/hip_runtime.h>
#include <hip/hip_bf16.h>
#include <cstddef>

#define EPSV 1e-5f

typedef __attribute__((ext_vector_type(8))) short bf16x8;
typedef __attribute__((ext_vector_type(4))) float f32x4;
typedef __attribute__((ext_vector_type(2))) float f32x2;
typedef __attribute__((ext_vector_type(4))) short short4v;
typedef __attribute__((ext_vector_type(4))) int int4v;

__device__ __forceinline__ float b2f(short s) {
  union { unsigned u; float f; } x;
  x.u = ((unsigned)(unsigned short)s) << 16;
  return x.f;
}
__device__ __forceinline__ short f2b(float f) {
  union { __hip_bfloat16 h; short s; } x;
  x.h = __float2bfloat16(f);
  return x.s;
}
__device__ __forceinline__ f32x2 lo2(f32x4 v) { return __builtin_shufflevector(v, v, 0, 1); }
__device__ __forceinline__ f32x2 hi2(f32x4 v) { return __builtin_shufflevector(v, v, 2, 3); }
__device__ __forceinline__ f32x2 pkfma(f32x2 a, f32x2 b, f32x2 c) {
#if __has_builtin(__builtin_elementwise_fma)
  return __builtin_elementwise_fma(a, b, c);   // -> v_pk_fma_f32 on CDNA
#else
  f32x2 d; d[0] = fmaf(a[0], b[0], c[0]); d[1] = fmaf(a[1], b[1], c[1]); return d;
#endif
}
// unpack one dword of 2 bf16 -> f32x2 (2 VALU ops, no LDS)
__device__ __forceinline__ f32x2 upk(int u) {
  union { int i; float f; } a, b;
  a.i = u << 16;
  b.i = u & 0xffff0000;
  f32x2 r; r[0] = a.f; r[1] = b.f; return r;
}
// 16-lane rotate on the VALU pipe (DPP row_ror) — ctrl must be a literal constant
template <int CTRL>
__device__ __forceinline__ float dpp_ror(float v) {
  return __int_as_float(__builtin_amdgcn_update_dpp(
      __float_as_int(v), __float_as_int(v), CTRL, 0xf, 0xf, false));
}

// ---- prep region layout (float offsets inside d_out) ----
// d_out floats: [0, 3211264) = xbT bf16 [896][56][128]  (as shorts)
// prep tail at 3,300,000 (transpose_out overwrites d_out last):
#define PF_W    3300000   // bf16 [8][32][128]  = 16384 f
#define PF_RQ   3316384   // bf16 [8][112][8]   = 3584 f  (scB-prescaled, row111 zero)
#define PF_RK   3327136   // bf16 [8][112][8]   = 3584 f  ((scC/scA)-prescaled)
#define PF_RV   3337888   // bf16 [8][16][136]  = 8704 f  (zero-padded d>=111)
#define PF_QSC  3346592   // f32 [256]  (k-rows scA-folded)
#define PF_QSH  3346848   // f32 [256]
#define PF_OSC  3347104   // f32 [256]
#define PF_OSH  3347360   // f32 [256]
#define PF_SH3  3347616   // f32 [8]

// Merged: blocks 0..7 = block-invariant prep (per-g tables);
//         blocks 8..903 = x transpose (16,128,56,56) f32 -> xbT bf16 [896][56][128].
__global__ __launch_bounds__(256) void k_prep_tin(
    const float* __restrict__ x, const float* __restrict__ wq,
    const float* __restrict__ rel,
    const float* __restrict__ qg, const float* __restrict__ qb,
    const float* __restrict__ qm, const float* __restrict__ qv,
    const float* __restrict__ sg, const float* __restrict__ sb,
    const float* __restrict__ sm, const float* __restrict__ svar,
    const float* __restrict__ og, const float* __restrict__ ob,
    const float* __restrict__ om, const float* __restrict__ ov,
    float* __restrict__ prep) {
  __shared__ short t2[128 * 57];
  const int tid = threadIdx.x;

  if (blockIdx.x < 8) {
    const int g = blockIdx.x;
    const float scA = sg[g] * rsqrtf(svar[g] + EPSV);
    const float scB = sg[8 + g] * rsqrtf(svar[8 + g] + EPSV);
    const float scC = sg[16 + g] * rsqrtf(svar[16 + g] + EPSV);
    const float rCA = scC / scA;

    short* wb = (short*)(prep + PF_W) + g * 4096;
    for (int t = tid; t < 1024; t += 256) {
      int o = t >> 5, c0 = (t & 31) * 4;
      float4 wv = *(const float4*)&wq[g * 4096 + o * 128 + c0];
      short4v s4 = {f2b(wv.x), f2b(wv.y), f2b(wv.z), f2b(wv.w)};
      *(short4v*)&wb[o * 128 + c0] = s4;
    }
    short* rq = (short*)(prep + PF_RQ) + g * 896;   // bf16 [112][8]
    short* rk = (short*)(prep + PF_RK) + g * 896;
    for (int t = tid; t < 896; t += 256) {
      int d = t >> 3, c = t & 7;
      rq[t] = (d < 111) ? f2b(rel[c * 111 + d] * scB) : (short)0;
      rk[t] = (d < 111) ? f2b(rel[(8 + c) * 111 + d] * rCA) : (short)0;
    }
    short* rv = (short*)(prep + PF_RV) + g * 2176;
    for (int t = tid; t < 2176; t += 256) {
      int c = t / 136, d = t - c * 136;
      rv[t] = (d < 111) ? f2b(rel[(16 + c) * 111 + d]) : (short)0;
    }
    if (tid < 32) {
      int ch = g * 32 + tid;
      float sc = qg[ch] * rsqrtf(qv[ch] + EPSV);
      float sh = qb[ch] - qm[ch] * sc;
      if (tid >= 8 && tid < 16) { sc *= scA; sh *= scA; }   // k' = scA * k_bn
      prep[PF_QSC + ch] = sc;
      prep[PF_QSH + ch] = sh;
      float so = og[ch] * rsqrtf(ov[ch] + EPSV);
      prep[PF_OSC + ch] = so;
      prep[PF_OSH + ch] = ob[ch] - om[ch] * so;
    }
    if (tid == 0) {
      float shA = sb[g] - sm[g] * scA;
      float shB = sb[8 + g] - sm[8 + g] * scB;
      float shC = sb[16 + g] - sm[16 + g] * scC;
      prep[PF_SH3 + g] = shA + shB + shC;
    }
  } else {
    const int nh = blockIdx.x - 8;          // n*56 + h
    const int n = nh / 56, h = nh - n * 56;
    unsigned* xbT = (unsigned*)prep;
    const float* src = x + (size_t)n * 401408 + h * 56;
    for (int t = tid; t < 1792; t += 256) {   // 128 c x 14 w-quads
      int c = t / 14, w4 = (t - c * 14) * 4;
      float4 v = *(const float4*)&src[c * 3136 + w4];
      t2[c * 57 + w4 + 0] = f2b(v.x);
      t2[c * 57 + w4 + 1] = f2b(v.y);
      t2[c * 57 + w4 + 2] = f2b(v.z);
      t2[c * 57 + w4 + 3] = f2b(v.w);
    }
    __syncthreads();
    for (int t = tid; t < 3584; t += 256) {   // 56 w x 64 c-pairs (u32)
      int w = t >> 6, cp = t & 63;
      unsigned lo = (unsigned short)t2[(2 * cp) * 57 + w];
      unsigned hi = (unsigned short)t2[(2 * cp + 1) * 57 + w];
      xbT[(((size_t)(n * 56 + w) * 56 + h) << 6) + cp] = lo | (hi << 16);
    }
  }
}

// tmp bf16 (896,128,56) -> out f32 (16,128,56,56): out[n][c][h][w] = tmp[n*56+w][c][h]
__global__ __launch_bounds__(256) void k_transpose_out(const short* __restrict__ tmp,
                                                       float* __restrict__ out) {
  int nc = blockIdx.x;
  int n = nc >> 7, c = nc & 127;
  __shared__ float t[56][57];
  for (int idx = threadIdx.x; idx < 3136; idx += 256) {
    int w = idx / 56, h = idx - w * 56;
    t[h][w] = b2f(tmp[((size_t)(n * 56 + w) * 128 + c) * 56 + h]);
  }
  __syncthreads();
  float* dst = out + (size_t)nc * 3136;
  for (int idx = threadIdx.x; idx < 3136; idx += 256)
    dst[idx] = t[idx / 56][idx % 56];
}

// LDS arena (offsets in shorts). Lifetime unions:
//  [0,7680):      xsT bf16 [56][136] (A..B) | simShift bf16 [64][120] (C..D, row-owner zeroed)
//  [7680,12288):  Ws bf16 [32][136] (A..B)  | simA bf16 [64][72] (C..D)
//  [12288,14528): qkT f32 [56][20] (B..C) | svL f32 [16][60] (D..E)
//  [14528,15424): rqB bf16 [112][8];  [15424,16320): rkB bf16 [112][8]
//  [16320,18496): relv bf16 [16][136]
//  [18496,19648): VBH bf16 [16][72];  [19648,20800): VBL bf16 [16][72]
#define O_XST    0
#define O_SHFT   0
#define O_WS     7680
#define O_SIMA   7680
#define O_QKT    12288
#define O_SVL    12288
#define O_RQTF   14528
#define O_RKTF   15424
#define O_RELV   16320
#define O_VBH    18496
#define O_VBL    19648
#define SB_SH    20800

// One block per (b,g): bid = g*896 + b. LDS ~42 KB -> 3 blocks/CU.
__global__ __launch_bounds__(512) void k_fused(
    const short* __restrict__ xbT, const float* __restrict__ prep,
    short* __restrict__ tmp) {
  const int tid = threadIdx.x;
  const int g = blockIdx.x / 896;
  const int b = blockIdx.x - g * 896;

  __shared__ __align__(16) short SB[SB_SH];
  __shared__ float s_qsc[32], s_qsh[32], s_osc[32], s_osh[32], s_sh3;

  const int lane = tid & 63;
  const int w = tid >> 6;          // wave 0..7
  const int m = lane & 15;
  const int qd = lane >> 4;        // 0..3
  const int it = w >> 1;           // tile row group 0..3
  const int half = w & 1;
  const int grp = tid >> 4;        // 16-lane group 0..31
  const int l16 = tid & 15;

  // ---------- phase A: pure-copy staging ----------
  {
    int4v z = {0, 0, 0, 0};
    int4v* zp = (int4v*)(SB + O_VBH);                 // VBH+VBL = 2304 sh = 288 int4
    for (int i = tid; i < 288; i += 512) zp[i] = z;

    const short* xsrc = xbT + (size_t)b * 7168;       // [56][128] bf16
    for (int t = tid; t < 896; t += 512) {            // 56 rows x 16 chunks
      int h = t >> 4, ck = (t & 15) * 8;
      *(bf16x8*)&SB[O_XST + h * 136 + ck] = *(const bf16x8*)&xsrc[h * 128 + ck];
    }
    const short* wsrc = (const short*)(prep + PF_W) + g * 4096;
    for (int t = tid; t < 512; t += 512) {            // 32 rows x 16 chunks
      int o = t >> 4, ck = (t & 15) * 8;
      *(bf16x8*)&SB[O_WS + o * 136 + ck] = *(const bf16x8*)&wsrc[o * 128 + ck];
    }
    const short* rqp = (const short*)(prep + PF_RQ) + g * 896;
    const short* rkp = (const short*)(prep + PF_RK) + g * 896;
    for (int t = tid; t < 224; t += 512) {
      if (t < 112) *(bf16x8*)&SB[O_RQTF + t * 8] = *(const bf16x8*)&rqp[t * 8];
      else         *(bf16x8*)&SB[O_RKTF + (t - 112) * 8] = *(const bf16x8*)&rkp[(t - 112) * 8];
    }
    const int4v* rvp = (const int4v*)((const short*)(prep + PF_RV) + g * 2176);
    int4v* rvd = (int4v*)(SB + O_RELV);
    for (int t = tid; t < 272; t += 512) rvd[t] = rvp[t];
    if (tid < 32) {
      s_qsc[tid] = prep[PF_QSC + g * 32 + tid];
      s_qsh[tid] = prep[PF_QSH + g * 32 + tid];
      s_osc[tid] = prep[PF_OSC + g * 32 + tid];
      s_osh[tid] = prep[PF_OSH + g * 32 + tid];
    }
    if (tid == 0) s_sh3 = prep[PF_SH3 + g];
  }
  __syncthreads();   // B0

  // ---------- phase B: qkv = BN(W @ x) via MFMA; q,k' -> qkT f32 (float4), v -> VBH/VBL ----------
  {
    const int o = half * 16 + m;
    const int h = it * 16 + m;
    f32x4 acc = {0.f, 0.f, 0.f, 0.f};
    __builtin_amdgcn_s_setprio(1);
#pragma unroll
    for (int ks = 0; ks < 4; ++ks) {
      bf16x8 av = *(bf16x8*)&SB[O_WS + o * 136 + qd * 8 + ks * 32];
      bf16x8 bv = *(bf16x8*)&SB[O_XST + h * 136 + qd * 8 + ks * 32];
      acc = __builtin_amdgcn_mfma_f32_16x16x32_bf16(av, bv, acc, 0, 0, 0);
    }
    __builtin_amdgcn_s_setprio(0);
    if (h < 56) {                    // D col = h; D row = oo = half*16+qd*4+r
      float* qkTf = (float*)(SB + O_QKT);
      if (half == 0) {               // all 4 rows are q/k' -> one float4 store
        float4 o4;
        o4.x = fmaf(acc[0], s_qsc[qd * 4 + 0], s_qsh[qd * 4 + 0]);
        o4.y = fmaf(acc[1], s_qsc[qd * 4 + 1], s_qsh[qd * 4 + 1]);
        o4.z = fmaf(acc[2], s_qsc[qd * 4 + 2], s_qsh[qd * 4 + 2]);
        o4.w = fmaf(acc[3], s_qsc[qd * 4 + 3], s_qsh[qd * 4 + 3]);
        *(float4*)&qkTf[h * 20 + qd * 4] = o4;
      } else {                       // all 4 rows are v -> hi/lo bf16
#pragma unroll
        for (int r = 0; r < 4; ++r) {
          int cv = qd * 4 + r;
          float val = fmaf(acc[r], s_qsc[16 + cv], s_qsh[16 + cv]);
          short vh = f2b(val);
          short vl = f2b(val - b2f(vh));
          SB[O_VBH + cv * 72 + h] = vh;
          SB[O_VBL + cv * 72 + h] = vl;
        }
      }
    }
  }
  __syncthreads();   // B1

  // ---------- phase C: row-zero simShift + logits (pkfma, bf16 tables) + DPP softmax + scatter ----------
  {
    const float* qkTf = (const float*)(SB + O_QKT);
    const float sh3 = s_sh3;
    const int4v z = {0, 0, 0, 0};

    // hoist k' (depends on l16/jt only)
    f32x4 kv0[4], kv1[4];
#pragma unroll
    for (int jt = 0; jt < 4; ++jt) {
      int j = jt * 16 + l16;
      int jj = (j < 56) ? j : 0;
      kv0[jt] = *(const f32x4*)&qkTf[jj * 20 + 8];
      kv1[jt] = *(const f32x4*)&qkTf[jj * 20 + 12];
    }

#pragma unroll
    for (int pass = 0; pass < 2; ++pass) {
      int i = pass * 32 + grp;
      // zero this group's simShift row (program order within wave: zero precedes scatter)
      if (i < 64 && l16 < 15) *(int4v*)&SB[O_SHFT + i * 120 + l16 * 8] = z;
      if (i < 56) {
        f32x4 qa4 = *(const f32x4*)&qkTf[i * 20 + 0];
        f32x4 qb4 = *(const f32x4*)&qkTf[i * 20 + 4];
        const f32x2 qlo = lo2(qa4), qhi = hi2(qa4);
        const f32x2 rlo = lo2(qb4), rhi = hi2(qb4);
        float L[4];
#pragma unroll
        for (int jt = 0; jt < 4; ++jt) {
          int j = jt * 16 + l16;
          if (j < 56) {
            const int4v rqv = *(const int4v*)&SB[O_RQTF + (i - j + 55) * 8];
            const int4v rkv = *(const int4v*)&SB[O_RKTF + (j - i + 55) * 8];
            const f32x4 k0 = kv0[jt], k1 = kv1[jt];
            f32x2 acc2 = {sh3, 0.f};
            acc2 = pkfma(qlo, lo2(k0), acc2);
            acc2 = pkfma(qhi, hi2(k0), acc2);
            acc2 = pkfma(rlo, lo2(k1), acc2);
            acc2 = pkfma(rhi, hi2(k1), acc2);
            acc2 = pkfma(qlo, upk(rqv[0]), acc2);
            acc2 = pkfma(qhi, upk(rqv[1]), acc2);
            acc2 = pkfma(rlo, upk(rqv[2]), acc2);
            acc2 = pkfma(rhi, upk(rqv[3]), acc2);
            acc2 = pkfma(lo2(k0), upk(rkv[0]), acc2);
            acc2 = pkfma(hi2(k0), upk(rkv[1]), acc2);
            acc2 = pkfma(lo2(k1), upk(rkv[2]), acc2);
            acc2 = pkfma(hi2(k1), upk(rkv[3]), acc2);
            L[jt] = acc2[0] + acc2[1];
          } else {
            L[jt] = -3.0e38f;
          }
        }
        float mx = fmaxf(fmaxf(L[0], L[1]), fmaxf(L[2], L[3]));
        mx = fmaxf(mx, dpp_ror<0x121>(mx));   // ror 1
        mx = fmaxf(mx, dpp_ror<0x122>(mx));   // ror 2
        mx = fmaxf(mx, dpp_ror<0x124>(mx));   // ror 4
        mx = fmaxf(mx, dpp_ror<0x128>(mx));   // ror 8
        float sum = 0.f, ex[4];
#pragma unroll
        for (int jt = 0; jt < 4; ++jt) {
          ex[jt] = __expf(L[jt] - mx);
          sum += ex[jt];
        }
        sum += dpp_ror<0x121>(sum);
        sum += dpp_ror<0x122>(sum);
        sum += dpp_ror<0x124>(sum);
        sum += dpp_ror<0x128>(sum);
        float inv = 1.0f / sum;
#pragma unroll
        for (int jt = 0; jt < 4; ++jt) {
          int j = jt * 16 + l16;
          if (j < 56) {
            short pv = f2b(ex[jt] * inv);
            SB[O_SIMA + i * 72 + j] = pv;                 // simA[i][j]
            SB[O_SHFT + i * 120 + (i - j + 55)] = pv;     // simShift[i][i-j+55]
          } else {
            SB[O_SIMA + i * 72 + j] = 0;                  // zero cols 56..63 (K-pad)
          }
        }
      }
    }
  }
  __syncthreads();   // B3

  // ---------- phase D: sv = P @ (vh+vl)^T (even waves), sve = relv @ simShift^T (odd) ----------
  f32x4 sveacc = {0.f, 0.f, 0.f, 0.f};
  {
    if (half == 0) {
      bf16x8 pa0 = *(bf16x8*)&SB[O_SIMA + (it * 16 + m) * 72 + qd * 8];
      bf16x8 pa1 = *(bf16x8*)&SB[O_SIMA + (it * 16 + m) * 72 + qd * 8 + 32];
      f32x4 acc = {0.f, 0.f, 0.f, 0.f};
      bf16x8 bv;
      __builtin_amdgcn_s_setprio(1);
      bv = *(bf16x8*)&SB[O_VBH + m * 72 + qd * 8];
      acc = __builtin_amdgcn_mfma_f32_16x16x32_bf16(pa0, bv, acc, 0, 0, 0);
      bv = *(bf16x8*)&SB[O_VBH + m * 72 + qd * 8 + 32];
      acc = __builtin_amdgcn_mfma_f32_16x16x32_bf16(pa1, bv, acc, 0, 0, 0);
      bv = *(bf16x8*)&SB[O_VBL + m * 72 + qd * 8];
      acc = __builtin_amdgcn_mfma_f32_16x16x32_bf16(pa0, bv, acc, 0, 0, 0);
      bv = *(bf16x8*)&SB[O_VBL + m * 72 + qd * 8 + 32];
      acc = __builtin_amdgcn_mfma_f32_16x16x32_bf16(pa1, bv, acc, 0, 0, 0);
      __builtin_amdgcn_s_setprio(0);
      float* svLf = (float*)(SB + O_SVL);
#pragma unroll
      for (int r = 0; r < 4; ++r) {
        int i2 = it * 16 + qd * 4 + r;             // D row = i
        if (i2 < 56) svLf[m * 60 + i2] = acc[r];   // svL[c=m][i]
      }
    } else {
      __builtin_amdgcn_s_setprio(1);
#pragma unroll
      for (int ks = 0; ks < 4; ++ks) {
        bf16x8 av = *(bf16x8*)&SB[O_RELV + m * 136 + qd * 8 + ks * 32];
        bf16x8 bv = *(bf16x8*)&SB[O_SHFT + (it * 16 + m) * 120 + qd * 8 + ks * 32];
        sveacc = __builtin_amdgcn_mfma_f32_16x16x32_bf16(av, bv, sveacc, 0, 0, 0);
      }
      __builtin_amdgcn_s_setprio(0);
      // sveacc[r] = sve[c=qd*4+r][i=it*16+m]
    }
  }
  __syncthreads();   // B4

  // ---------- phase E: odd waves combine sv+sve with out-BN, store tmp (bf16) ----------
  if (half == 1) {
    const int i2 = it * 16 + m;
    if (i2 < 56) {
      const float* svLf = (const float*)(SB + O_SVL);
#pragma unroll
      for (int r = 0; r < 4; ++r) {
        int c = qd * 4 + r;
        float svv = svLf[c * 60 + i2];
        float o = fmaf(svv, s_osc[2 * c], s_osh[2 * c]) +
                  fmaf(sveacc[r], s_osc[2 * c + 1], s_osh[2 * c + 1]);
        tmp[((size_t)b * 128 + g * 16 + c) * 56 + i2] = f2b(o);
      }
    }
  }
}

extern "C" void kernel_launch(void* const* d_in, const int* in_sizes, int n_in,
                              void* d_out, int out_size, void* d_ws, size_t ws_size,
                              hipStream_t stream) {
  const float* x   = (const float*)d_in[0];
  const float* wq  = (const float*)d_in[1];
  const float* rel = (const float*)d_in[2];
  const float* qg = (const float*)d_in[3];
  const float* qb = (const float*)d_in[4];
  const float* qm = (const float*)d_in[5];
  const float* qv = (const float*)d_in[6];
  const float* sg = (const float*)d_in[7];
  const float* sb = (const float*)d_in[8];
  const float* sm = (const float*)d_in[9];
  const float* sv = (const float*)d_in[10];
  const float* og = (const float*)d_in[11];
  const float* ob = (const float*)d_in[12];
  const float* om = (const float*)d_in[13];
  const float* ov = (const float*)d_in[14];
  float* out = (float*)d_out;

  // d_out doubles as staging: xbT bf16 [0,12.8MB) + prep tables at 13.2MB.
  // Both fully consumed before k_transpose_out overwrites d_out.
  short* tmp = (short*)d_ws;    // bf16 tmp, 12.8 MB

  k_prep_tin<<<904, 256, 0, stream>>>(x, wq, rel, qg, qb, qm, qv,
                                      sg, sb, sm, sv, og, ob, om, ov, out);
  k_fused<<<7168, 512, 0, stream>>>((const short*)out, out, tmp);
  k_transpose_out<<<2048, 256, 0, stream>>>(tmp, out);
}